// Round 7
// baseline (174.937 us; speedup 1.0000x reference)
//
#include <hip/hip_runtime.h>
#include <math.h>

// B,S,D,V,N_BLOCKS = 4096,128,9,5,4
constexpr int Bn = 4096;
constexpr int Sn = 128;
constexpr int Dn = 9;
constexpr int Vn = 5;
constexpr int NBn = 4;

typedef float f4 __attribute__((ext_vector_type(4)));
typedef _Float16 h8 __attribute__((ext_vector_type(8)));   // MFMA operand
typedef __fp16   h2 __attribute__((ext_vector_type(2)));   // cvt_pkrtz result
typedef __fp16   hv8 __attribute__((ext_vector_type(8)));
typedef unsigned u4v __attribute__((ext_vector_type(4)));
typedef short    s4v __attribute__((ext_vector_type(4)));

// LDS (bytes). Two ping-pong 128-row buffers in 32-slot fp16 "X-format":
//   slots [Xh(9)@0..8 | Xl(9)@9..17 | Xh-dup@18..26 | 0@27..29 | ch@30 | cl@31]
// Row stride 40 shorts = 80 B (16B-aligned rows, bank-spread b128 access).
// The SAME format serves as scores B ("G-format": [Gh|Gh|Gl|0|1|1]) so one
// MFMA computes (Xh+Xl)(Gh+Gl)+c per tile.  VF = V^T fp16 [16][136].
// MB/VB = B-operand frags for G=X*M~ and V=X*Wv^T (row=col n, 32 slots).
constexpr int B0_OFF = 0;        // 10240
constexpr int B1_OFF = 10240;    // 10240
constexpr int VF_OFF = 20480;    // 4352
constexpr int MB_OFF = 24832;    // 1024
constexpr int VB_OFF = 25856;    // 1024
constexpr int SMEM_BYTES = 26880;

static __device__ __forceinline__ void split_hl(float v, short& h, short& l) {
    _Float16 hv = (_Float16)v;
    h = __builtin_bit_cast(short, hv);
    l = __builtin_bit_cast(short, (_Float16)(v - (float)hv));
}

// One block = one batch, 4 waves. Per layer:
//   build: M~ = qscale*Wq^T*Wk (col 9 = qscale*Wk^T*bq), VB = Wv^T  (threads<177)
//   G/V:   wave w, tiles {2w,2w+1}: G~=X*M~ (c in col 9), V=X*Wv^T+bv via MFMA;
//          scatter G->Gb rows, c->Xb[30..31], V->VF, consts->Gb[27..31]
//   scores: S^T[key][q] = one MFMA (K=32 slots carry hi/lo + c), softmax (exp2),
//          PV fp16, O^T scattered into Gb rows (= next layer's X). Ping-pong.
__global__ __launch_bounds__(256, 5) void bert_kernel(
    const int*   __restrict__ tokens,
    const float* __restrict__ emb,
    const float* __restrict__ Wq, const float* __restrict__ bq,
    const float* __restrict__ Wk, const float* __restrict__ bk,
    const float* __restrict__ Wv, const float* __restrict__ bv,
    const float* __restrict__ Wout, const float* __restrict__ bout,
    float*       __restrict__ out)
{
    __shared__ __align__(16) char smem[SMEM_BYTES];
    short* BUF0 = (short*)(smem + B0_OFF);
    short* BUF1 = (short*)(smem + B1_OFF);
    short* VF   = (short*)(smem + VF_OFF);
    short* MB   = (short*)(smem + MB_OFF);
    short* VB   = (short*)(smem + VB_OFF);

    const int b   = blockIdx.x;
    const int tid = threadIdx.x;
    const int t   = tid & 63;
    const int w   = tid >> 6;
    const int col = t & 15;
    const int g   = t >> 4;
    const float qscale = (1.0f / 3.0f) * 1.44269504f;   // 1/sqrt(D) * log2(e)

    // ---- embed + pos-encoding -> BUF0 rows; zero MB/VB pad slots ----
    if (tid < 128) {
        const float inv_freq[Dn] = {
            1.0f, 1.0f, 0.1291549665f, 0.1291549665f,
            0.0166810054f, 0.0166810054f, 0.0021544347f, 0.0021544347f,
            0.0002782559f
        };
        const int r = tid;
        const int tok = tokens[b * Sn + r];
        unsigned short sl[32];
        #pragma unroll
        for (int d = 0; d < Dn; ++d) {
            const float a = (float)r * inv_freq[d];
            const float p = (d & 1) ? cosf(a) : sinf(a);
            const float xv = emb[tok * Dn + d] + p;
            short hh, ll; split_hl(xv, hh, ll);
            sl[d] = (unsigned short)hh;
            sl[9 + d] = (unsigned short)ll;
            sl[18 + d] = (unsigned short)hh;
        }
        #pragma unroll
        for (int d = 27; d < 32; ++d) sl[d] = 0;
        unsigned wb[16];
        #pragma unroll
        for (int j = 0; j < 16; ++j)
            wb[j] = (unsigned)sl[2 * j] | ((unsigned)sl[2 * j + 1] << 16);
        u4v* rp = (u4v*)(BUF0 + r * 40);
        rp[0] = (u4v){wb[0], wb[1], wb[2], wb[3]};
        rp[1] = (u4v){wb[4], wb[5], wb[6], wb[7]};
        rp[2] = (u4v){wb[8], wb[9], wb[10], wb[11]};
        rp[3] = (u4v){wb[12], wb[13], wb[14], wb[15]};
    } else if (tid < 144) {
        const int n = tid - 128;
        MB[n * 32 + 27] = 0;
        *(unsigned*)(MB + n * 32 + 28) = 0u;
        *(unsigned*)(MB + n * 32 + 30) = 0u;
    } else if (tid < 160) {
        const int n = tid - 144;
        VB[n * 32 + 27] = 0;
        *(unsigned*)(VB + n * 32 + 28) = 0u;
        *(unsigned*)(VB + n * 32 + 30) = 0u;
    }

    #pragma unroll 1
    for (int it = 0; it < NBn; ++it) {
        short* Xb = (it & 1) ? BUF1 : BUF0;
        short* Gb = (it & 1) ? BUF0 : BUF1;

        // ---- build MB (M~ incl. c-column) and VB ----
        {
            const float* wq  = Wq + it * 81;
            const float* wk  = Wk + it * 81;
            const float* wv  = Wv + it * 81;
            const float* bqi = bq + it * 9;
            if (tid < 90) {
                const int d = tid % 9, n = tid / 9;   // n 0..9 (9 = u column)
                float a = 0.0f;
                if (n < 9) {
                    #pragma unroll
                    for (int e = 0; e < 9; ++e) a = fmaf(wq[e * 9 + d], wk[e * 9 + n], a);
                } else {
                    #pragma unroll
                    for (int e = 0; e < 9; ++e) a = fmaf(wk[e * 9 + d], bqi[e], a);
                }
                a *= qscale;
                short hh, ll; split_hl(a, hh, ll);
                MB[n * 32 + d] = hh; MB[n * 32 + 9 + d] = hh; MB[n * 32 + 18 + d] = ll;
            }
            if (tid >= 96 && tid < 177) {
                const int j = tid - 96, d = j % 9, e = j / 9;
                short hh, ll; split_hl(wv[e * 9 + d], hh, ll);
                VB[e * 32 + d] = hh; VB[e * 32 + 9 + d] = hh; VB[e * 32 + 18 + d] = ll;
            }
        }
        __syncthreads();   // embed/build/prev-O-scatter complete

        // ---- G/V phase: wave w does m-tiles {2w, 2w+1} ----
        {
            const float* bvi = bv + it * 9;
            h8 mbf = *(const h8*)(MB + col * 32 + g * 8);
            h8 vbf = *(const h8*)(VB + col * 32 + g * 8);
            const float bvv = (col < 9) ? bvi[col] : 0.0f;
            f4 cinit = {bvv, bvv, bvv, bvv};
            #pragma unroll
            for (int ti = 0; ti < 2; ++ti) {
                const int mt = 2 * w + ti;
                h8 xa = *(const h8*)(Xb + (mt * 16 + col) * 40 + g * 8);
                f4 gt = __builtin_amdgcn_mfma_f32_16x16x32_f16(xa, mbf, (f4)(0.0f), 0, 0, 0);
                f4 vt = __builtin_amdgcn_mfma_f32_16x16x32_f16(xa, vbf, cinit, 0, 0, 0);
                const int r0 = mt * 16 + 4 * g;
                if (col < 9) {
                    #pragma unroll
                    for (int rr = 0; rr < 4; ++rr) {
                        VF[col * 136 + r0 + rr] = __builtin_bit_cast(short, (_Float16)vt[rr]);
                        short hh, ll; split_hl(gt[rr], hh, ll);
                        short* rowp = Gb + (r0 + rr) * 40;
                        rowp[col] = hh; rowp[9 + col] = hh; rowp[18 + col] = ll;
                    }
                } else if (col == 9) {       // c column -> Xb slots 30/31
                    #pragma unroll
                    for (int rr = 0; rr < 4; ++rr) {
                        short hh, ll; split_hl(gt[rr], hh, ll);
                        unsigned pk = (unsigned)(unsigned short)hh
                                    | ((unsigned)(unsigned short)ll << 16);
                        *(unsigned*)(Xb + (r0 + rr) * 40 + 30) = pk;
                    }
                } else if (col == 10) {      // consts for G-format rows
                    #pragma unroll
                    for (int rr = 0; rr < 4; ++rr) {
                        short* rowp = Gb + (r0 + rr) * 40;
                        rowp[27] = 0;
                        *(unsigned*)(rowp + 28) = 0u;
                        *(unsigned*)(rowp + 30) = 0x3C003C00u;   // fp16 1.0,1.0
                    }
                }
            }
        }
        __syncthreads();   // Gb rows, c-slots, VF ready

        // ---- scores + softmax + PV; wave w does q-tiles {2w, 2w+1} ----
        h8 kfr[8];
        #pragma unroll
        for (int kt = 0; kt < 8; ++kt)
            kfr[kt] = *(const h8*)(Xb + (kt * 16 + col) * 40 + g * 8);

        h8 vfr[4];   // V^T A-frags, permuted keys: slot(g,j) <-> 16*(2s+(j>>2))+4g+(j&3)
        #pragma unroll
        for (int s = 0; s < 4; ++s) {
            const short* p0 = VF + col * 136 + 32 * s + 4 * g;
            s4v va = *(const s4v*)p0;
            s4v vb2 = *(const s4v*)(p0 + 16);
            vfr[s] = __builtin_bit_cast(h8,
                __builtin_shufflevector(va, vb2, 0, 1, 2, 3, 4, 5, 6, 7));
        }

        #pragma unroll
        for (int ti = 0; ti < 2; ++ti) {
            const int qt = 2 * w + ti;
            const int q  = qt * 16 + col;
            h8 bg = *(const h8*)(Gb + q * 40 + g * 8);

            f4 acc[8];
            #pragma unroll
            for (int kt = 0; kt < 8; ++kt)
                acc[kt] = __builtin_amdgcn_mfma_f32_16x16x32_f16(kfr[kt], bg, (f4)(0.0f), 0, 0, 0);

            // lane holds S^T[key = kt*16 + 4g + rr][q] (log2 domain, c included)
            f4 m0 = __builtin_elementwise_max(acc[0], acc[1]);
            f4 m1 = __builtin_elementwise_max(acc[2], acc[3]);
            f4 m2 = __builtin_elementwise_max(acc[4], acc[5]);
            f4 m3 = __builtin_elementwise_max(acc[6], acc[7]);
            f4 m4 = __builtin_elementwise_max(__builtin_elementwise_max(m0, m1),
                                              __builtin_elementwise_max(m2, m3));
            float mx = fmaxf(fmaxf(m4.x, m4.y), fmaxf(m4.z, m4.w));
            mx = fmaxf(mx, __shfl_xor(mx, 16));
            mx = fmaxf(mx, __shfl_xor(mx, 32));

            float sm = 0.0f;
            #pragma unroll
            for (int kt = 0; kt < 8; ++kt)
                #pragma unroll
                for (int rr = 0; rr < 4; ++rr) {
                    float e2 = __builtin_amdgcn_exp2f(acc[kt][rr] - mx);
                    acc[kt][rr] = e2;
                    sm += e2;
                }
            sm += __shfl_xor(sm, 16);
            sm += __shfl_xor(sm, 32);

            f4 oac = (f4)(0.0f);
            #pragma unroll
            for (int s = 0; s < 4; ++s) {
                u4v up = (u4v){
                    __builtin_bit_cast(unsigned, __builtin_amdgcn_cvt_pkrtz(acc[2*s][0],   acc[2*s][1])),
                    __builtin_bit_cast(unsigned, __builtin_amdgcn_cvt_pkrtz(acc[2*s][2],   acc[2*s][3])),
                    __builtin_bit_cast(unsigned, __builtin_amdgcn_cvt_pkrtz(acc[2*s+1][0], acc[2*s+1][1])),
                    __builtin_bit_cast(unsigned, __builtin_amdgcn_cvt_pkrtz(acc[2*s+1][2], acc[2*s+1][3])) };
                oac = __builtin_amdgcn_mfma_f32_16x16x32_f16(vfr[s], __builtin_bit_cast(h8, up), oac, 0, 0, 0);
            }
            const float rl = 1.0f / sm;
            oac *= rl;

            // O^T (lane: col=q, rows d=4g+rr) -> Gb row q in X-format (d<9)
            if (g < 2) {
                h2 p01 = __builtin_amdgcn_cvt_pkrtz(oac.x, oac.y);
                h2 p23 = __builtin_amdgcn_cvt_pkrtz(oac.z, oac.w);
                short* rowp = Gb + q * 40;
                *(unsigned*)(rowp + 4 * g)          = __builtin_bit_cast(unsigned, p01);
                *(unsigned*)(rowp + 4 * g + 2)      = __builtin_bit_cast(unsigned, p23);
                *(unsigned*)(rowp + 18 + 4 * g)     = __builtin_bit_cast(unsigned, p01);
                *(unsigned*)(rowp + 18 + 4 * g + 2) = __builtin_bit_cast(unsigned, p23);
                rowp[9 + 4 * g + 0] = __builtin_bit_cast(short, (_Float16)(oac.x - (float)p01.x));
                rowp[9 + 4 * g + 1] = __builtin_bit_cast(short, (_Float16)(oac.y - (float)p01.y));
                rowp[9 + 4 * g + 2] = __builtin_bit_cast(short, (_Float16)(oac.z - (float)p23.x));
                rowp[9 + 4 * g + 3] = __builtin_bit_cast(short, (_Float16)(oac.w - (float)p23.y));
            } else if (g == 2) {
                short hh, ll; split_hl(oac.x, hh, ll);
                short* rowp = Gb + q * 40;
                rowp[8] = hh; rowp[17] = ll; rowp[26] = hh;
            }
        }
        // layer-top sync of next iteration protects Gb->Xb handoff
    }
    __syncthreads();

    // ---- logits + log_softmax from BUF0 (final X after 4 ping-pongs) ----
    if (tid < 128) {
        const int r = tid;
        const short* rowp = BUF0 + r * 40;
        hv8 ha = __builtin_bit_cast(hv8, *(const u4v*)rowp);          // slots 0..7
        hv8 hb = __builtin_bit_cast(hv8, *(const u4v*)(rowp + 8));    // slots 8..15
        h2  hc = __builtin_bit_cast(h2, *(const unsigned*)(rowp + 16)); // 16,17
        float x[9];
        x[0] = (float)ha[0] + (float)hb[1];
        x[1] = (float)ha[1] + (float)hb[2];
        x[2] = (float)ha[2] + (float)hb[3];
        x[3] = (float)ha[3] + (float)hb[4];
        x[4] = (float)ha[4] + (float)hb[5];
        x[5] = (float)ha[5] + (float)hb[6];
        x[6] = (float)ha[6] + (float)hb[7];
        x[7] = (float)ha[7] + (float)hc.x;
        x[8] = (float)hb[0] + (float)hc.y;
        float lg[Vn];
        #pragma unroll
        for (int v = 0; v < Vn; ++v) {
            float a = bout[v];
            #pragma unroll
            for (int d = 0; d < Dn; ++d) a = fmaf(x[d], Wout[v * Dn + d], a);
            lg[v] = a;
        }
        float mm = lg[0];
        #pragma unroll
        for (int v = 1; v < Vn; ++v) mm = fmaxf(mm, lg[v]);
        float sum = 0.0f;
        #pragma unroll
        for (int v = 0; v < Vn; ++v)
            sum += __builtin_amdgcn_exp2f((lg[v] - mm) * 1.44269504f);
        const float lse = __builtin_amdgcn_logf(sum) * 0.69314718f + mm;
        float* op = out + ((size_t)b * Sn + r) * Vn;
        #pragma unroll
        for (int v = 0; v < Vn; ++v) op[v] = lg[v] - lse;
    }
}

extern "C" void kernel_launch(void* const* d_in, const int* in_sizes, int n_in,
                              void* d_out, int out_size, void* d_ws, size_t ws_size,
                              hipStream_t stream) {
    const int*   tokens = (const int*)  d_in[0];
    const float* emb    = (const float*)d_in[1];
    const float* Wq     = (const float*)d_in[2];
    const float* bq_    = (const float*)d_in[3];
    const float* Wk     = (const float*)d_in[4];
    const float* bk_    = (const float*)d_in[5];
    const float* Wv     = (const float*)d_in[6];
    const float* bv_    = (const float*)d_in[7];
    const float* Wout   = (const float*)d_in[8];
    const float* bout_  = (const float*)d_in[9];
    float* out = (float*)d_out;

    bert_kernel<<<dim3(Bn), dim3(256), 0, stream>>>(
        tokens, emb, Wq, bq_, Wk, bk_, Wv, bv_, Wout, bout_, out);
}

// Round 8
// 163.443 us; speedup vs baseline: 1.0703x; 1.0703x over previous
//
#include <hip/hip_runtime.h>
#include <math.h>

// B,S,D,V,N_BLOCKS = 4096,128,9,5,4
constexpr int Bn = 4096;
constexpr int Sn = 128;
constexpr int Dn = 9;
constexpr int Vn = 5;
constexpr int NBn = 4;

typedef float f4 __attribute__((ext_vector_type(4)));
typedef _Float16 h8 __attribute__((ext_vector_type(8)));   // MFMA operand
typedef __fp16   h2 __attribute__((ext_vector_type(2)));   // cvt_pkrtz result
typedef __fp16   hv8 __attribute__((ext_vector_type(8)));
typedef unsigned u4v __attribute__((ext_vector_type(4)));
typedef short    s4v __attribute__((ext_vector_type(4)));

// LDS (bytes). Two ping-pong 128-row buffers in 32-slot fp16 "X-format":
//   slots [Xh(9)@0..8 | Xl(9)@9..17 | Xh-dup@18..26 | 0@27..29 | ch@30 | cl@31]
// Row stride 40 shorts = 80 B (16B-aligned rows, bank-spread b128 access).
// The SAME format serves as scores B ("G-format": [Gh|Gh|Gl|0|1|1]) so one
// MFMA computes (Xh+Xl)(Gh+Gl)+c per tile.  VF = V^T fp16 [16][136].
// MB/VB = B-operand frags for G=X*M~ and V=X*Wv^T (row=col n, 32 slots).
constexpr int B0_OFF = 0;        // 10240
constexpr int B1_OFF = 10240;    // 10240
constexpr int VF_OFF = 20480;    // 4352
constexpr int MB_OFF = 24832;    // 1024
constexpr int VB_OFF = 25856;    // 1024
constexpr int SMEM_BYTES = 26880;

static __device__ __forceinline__ void split_hl(float v, short& h, short& l) {
    _Float16 hv = (_Float16)v;
    h = __builtin_bit_cast(short, hv);
    l = __builtin_bit_cast(short, (_Float16)(v - (float)hv));
}

// One block = one batch, 4 waves. Per layer:
//   build: M~ = qscale*Wq^T*Wk (col 9 = qscale*Wk^T*bq), VB = Wv^T  (threads<177)
//   G/V:   wave w, tiles {2w,2w+1}: G~=X*M~ (c in col 9), V=X*Wv^T+bv via MFMA;
//          scatter G->Gb rows, c->Xb[30..31], V->VF, consts->Gb[27..31]
//   scores: S^T[key][q] = one MFMA (K=32 slots carry hi/lo + c), softmax (exp2),
//          PV fp16, O^T scattered into Gb rows (= next layer's X). Ping-pong.
// launch_bounds(256,4): reg budget 128/wave (incl AGPR) — (256,5) spilled
// ~66 MB scratch/dispatch in round 7. Do not tighten.
__global__ __launch_bounds__(256, 4) void bert_kernel(
    const int*   __restrict__ tokens,
    const float* __restrict__ emb,
    const float* __restrict__ Wq, const float* __restrict__ bq,
    const float* __restrict__ Wk, const float* __restrict__ bk,
    const float* __restrict__ Wv, const float* __restrict__ bv,
    const float* __restrict__ Wout, const float* __restrict__ bout,
    float*       __restrict__ out)
{
    __shared__ __align__(16) char smem[SMEM_BYTES];
    short* BUF0 = (short*)(smem + B0_OFF);
    short* BUF1 = (short*)(smem + B1_OFF);
    short* VF   = (short*)(smem + VF_OFF);
    short* MB   = (short*)(smem + MB_OFF);
    short* VB   = (short*)(smem + VB_OFF);

    const int b   = blockIdx.x;
    const int tid = threadIdx.x;
    const int t   = tid & 63;
    const int w   = tid >> 6;
    const int col = t & 15;
    const int g   = t >> 4;
    const float qscale = (1.0f / 3.0f) * 1.44269504f;   // 1/sqrt(D) * log2(e)

    // ---- embed + pos-encoding -> BUF0 rows; zero MB/VB pad slots ----
    if (tid < 128) {
        const float inv_freq[Dn] = {
            1.0f, 1.0f, 0.1291549665f, 0.1291549665f,
            0.0166810054f, 0.0166810054f, 0.0021544347f, 0.0021544347f,
            0.0002782559f
        };
        const int r = tid;
        const int tok = tokens[b * Sn + r];
        unsigned short sl[32];
        #pragma unroll
        for (int d = 0; d < Dn; ++d) {
            const float a = (float)r * inv_freq[d];
            const float p = (d & 1) ? __cosf(a) : __sinf(a);
            const float xv = emb[tok * Dn + d] + p;
            short hh, ll; split_hl(xv, hh, ll);
            sl[d] = (unsigned short)hh;
            sl[9 + d] = (unsigned short)ll;
            sl[18 + d] = (unsigned short)hh;
        }
        #pragma unroll
        for (int d = 27; d < 32; ++d) sl[d] = 0;
        unsigned wb[16];
        #pragma unroll
        for (int j = 0; j < 16; ++j)
            wb[j] = (unsigned)sl[2 * j] | ((unsigned)sl[2 * j + 1] << 16);
        u4v* rp = (u4v*)(BUF0 + r * 40);
        rp[0] = (u4v){wb[0], wb[1], wb[2], wb[3]};
        rp[1] = (u4v){wb[4], wb[5], wb[6], wb[7]};
        rp[2] = (u4v){wb[8], wb[9], wb[10], wb[11]};
        rp[3] = (u4v){wb[12], wb[13], wb[14], wb[15]};
    } else if (tid < 144) {
        const int n = tid - 128;
        MB[n * 32 + 27] = 0;
        *(unsigned*)(MB + n * 32 + 28) = 0u;
        *(unsigned*)(MB + n * 32 + 30) = 0u;
    } else if (tid < 160) {
        const int n = tid - 144;
        VB[n * 32 + 27] = 0;
        *(unsigned*)(VB + n * 32 + 28) = 0u;
        *(unsigned*)(VB + n * 32 + 30) = 0u;
    }

    #pragma unroll 1
    for (int it = 0; it < NBn; ++it) {
        short* Xb = (it & 1) ? BUF1 : BUF0;
        short* Gb = (it & 1) ? BUF0 : BUF1;

        // ---- build MB (M~ incl. c-column) and VB ----
        {
            const float* wq  = Wq + it * 81;
            const float* wk  = Wk + it * 81;
            const float* wv  = Wv + it * 81;
            const float* bqi = bq + it * 9;
            if (tid < 90) {
                const int d = tid % 9, n = tid / 9;   // n 0..9 (9 = c column)
                float a = 0.0f;
                if (n < 9) {
                    #pragma unroll
                    for (int e = 0; e < 9; ++e) a = fmaf(wq[e * 9 + d], wk[e * 9 + n], a);
                } else {
                    #pragma unroll
                    for (int e = 0; e < 9; ++e) a = fmaf(wk[e * 9 + d], bqi[e], a);
                }
                a *= qscale;
                short hh, ll; split_hl(a, hh, ll);
                MB[n * 32 + d] = hh; MB[n * 32 + 9 + d] = hh; MB[n * 32 + 18 + d] = ll;
            }
            if (tid >= 96 && tid < 177) {
                const int j = tid - 96, d = j % 9, e = j / 9;
                short hh, ll; split_hl(wv[e * 9 + d], hh, ll);
                VB[e * 32 + d] = hh; VB[e * 32 + 9 + d] = hh; VB[e * 32 + 18 + d] = ll;
            }
        }
        __syncthreads();   // embed/build/prev-O-scatter complete

        // ---- G/V phase: wave w does m-tiles {2w, 2w+1} ----
        {
            const float* bvi = bv + it * 9;
            h8 mbf = *(const h8*)(MB + col * 32 + g * 8);
            h8 vbf = *(const h8*)(VB + col * 32 + g * 8);
            const float bvv = (col < 9) ? bvi[col] : 0.0f;
            f4 cinit = {bvv, bvv, bvv, bvv};
            #pragma unroll
            for (int ti = 0; ti < 2; ++ti) {
                const int mt = 2 * w + ti;
                h8 xa = *(const h8*)(Xb + (mt * 16 + col) * 40 + g * 8);
                f4 gt = __builtin_amdgcn_mfma_f32_16x16x32_f16(xa, mbf, (f4)(0.0f), 0, 0, 0);
                f4 vt = __builtin_amdgcn_mfma_f32_16x16x32_f16(xa, vbf, cinit, 0, 0, 0);
                const int r0 = mt * 16 + 4 * g;
                if (col < 9) {
                    #pragma unroll
                    for (int rr = 0; rr < 4; ++rr) {
                        VF[col * 136 + r0 + rr] = __builtin_bit_cast(short, (_Float16)vt[rr]);
                        short hh, ll; split_hl(gt[rr], hh, ll);
                        short* rowp = Gb + (r0 + rr) * 40;
                        rowp[col] = hh; rowp[9 + col] = hh; rowp[18 + col] = ll;
                    }
                } else if (col == 9) {       // c column -> Xb slots 30/31
                    #pragma unroll
                    for (int rr = 0; rr < 4; ++rr) {
                        short hh, ll; split_hl(gt[rr], hh, ll);
                        unsigned pk = (unsigned)(unsigned short)hh
                                    | ((unsigned)(unsigned short)ll << 16);
                        *(unsigned*)(Xb + (r0 + rr) * 40 + 30) = pk;
                    }
                } else if (col == 10) {      // consts for G-format rows
                    #pragma unroll
                    for (int rr = 0; rr < 4; ++rr) {
                        short* rowp = Gb + (r0 + rr) * 40;
                        rowp[27] = 0;
                        *(unsigned*)(rowp + 28) = 0u;
                        *(unsigned*)(rowp + 30) = 0x3C003C00u;   // fp16 1.0,1.0
                    }
                }
            }
        }
        __syncthreads();   // Gb rows, c-slots, VF ready

        // ---- scores + softmax + PV; wave w does q-tiles {2w, 2w+1} ----
        h8 kfr[8];
        #pragma unroll
        for (int kt = 0; kt < 8; ++kt)
            kfr[kt] = *(const h8*)(Xb + (kt * 16 + col) * 40 + g * 8);

        h8 vfr[4];   // V^T A-frags, permuted keys: slot(g,j) <-> 16*(2s+(j>>2))+4g+(j&3)
        #pragma unroll
        for (int s = 0; s < 4; ++s) {
            const short* p0 = VF + col * 136 + 32 * s + 4 * g;
            s4v va = *(const s4v*)p0;
            s4v vb2 = *(const s4v*)(p0 + 16);
            vfr[s] = __builtin_bit_cast(h8,
                __builtin_shufflevector(va, vb2, 0, 1, 2, 3, 4, 5, 6, 7));
        }

        #pragma unroll
        for (int ti = 0; ti < 2; ++ti) {
            const int qt = 2 * w + ti;
            const int q  = qt * 16 + col;
            h8 bg = *(const h8*)(Gb + q * 40 + g * 8);

            f4 acc[8];
            #pragma unroll
            for (int kt = 0; kt < 8; ++kt)
                acc[kt] = __builtin_amdgcn_mfma_f32_16x16x32_f16(kfr[kt], bg, (f4)(0.0f), 0, 0, 0);

            // lane holds S^T[key = kt*16 + 4g + rr][q] (log2 domain, c included)
            f4 m0 = __builtin_elementwise_max(acc[0], acc[1]);
            f4 m1 = __builtin_elementwise_max(acc[2], acc[3]);
            f4 m2 = __builtin_elementwise_max(acc[4], acc[5]);
            f4 m3 = __builtin_elementwise_max(acc[6], acc[7]);
            f4 m4 = __builtin_elementwise_max(__builtin_elementwise_max(m0, m1),
                                              __builtin_elementwise_max(m2, m3));
            float mx = fmaxf(fmaxf(m4.x, m4.y), fmaxf(m4.z, m4.w));
            mx = fmaxf(mx, __shfl_xor(mx, 16));
            mx = fmaxf(mx, __shfl_xor(mx, 32));

            float sm = 0.0f;
            #pragma unroll
            for (int kt = 0; kt < 8; ++kt)
                #pragma unroll
                for (int rr = 0; rr < 4; ++rr) {
                    float e2 = __builtin_amdgcn_exp2f(acc[kt][rr] - mx);
                    acc[kt][rr] = e2;
                    sm += e2;
                }
            sm += __shfl_xor(sm, 16);
            sm += __shfl_xor(sm, 32);

            f4 oac = (f4)(0.0f);
            #pragma unroll
            for (int s = 0; s < 4; ++s) {
                u4v up = (u4v){
                    __builtin_bit_cast(unsigned, __builtin_amdgcn_cvt_pkrtz(acc[2*s][0],   acc[2*s][1])),
                    __builtin_bit_cast(unsigned, __builtin_amdgcn_cvt_pkrtz(acc[2*s][2],   acc[2*s][3])),
                    __builtin_bit_cast(unsigned, __builtin_amdgcn_cvt_pkrtz(acc[2*s+1][0], acc[2*s+1][1])),
                    __builtin_bit_cast(unsigned, __builtin_amdgcn_cvt_pkrtz(acc[2*s+1][2], acc[2*s+1][3])) };
                oac = __builtin_amdgcn_mfma_f32_16x16x32_f16(vfr[s], __builtin_bit_cast(h8, up), oac, 0, 0, 0);
            }
            const float rl = 1.0f / sm;
            oac *= rl;

            // O^T (lane: col=q, rows d=4g+rr) -> Gb row q in X-format (d<9)
            if (g < 2) {
                h2 p01 = __builtin_amdgcn_cvt_pkrtz(oac.x, oac.y);
                h2 p23 = __builtin_amdgcn_cvt_pkrtz(oac.z, oac.w);
                short* rowp = Gb + q * 40;
                *(unsigned*)(rowp + 4 * g)          = __builtin_bit_cast(unsigned, p01);
                *(unsigned*)(rowp + 4 * g + 2)      = __builtin_bit_cast(unsigned, p23);
                *(unsigned*)(rowp + 18 + 4 * g)     = __builtin_bit_cast(unsigned, p01);
                *(unsigned*)(rowp + 18 + 4 * g + 2) = __builtin_bit_cast(unsigned, p23);
                rowp[9 + 4 * g + 0] = __builtin_bit_cast(short, (_Float16)(oac.x - (float)p01.x));
                rowp[9 + 4 * g + 1] = __builtin_bit_cast(short, (_Float16)(oac.y - (float)p01.y));
                rowp[9 + 4 * g + 2] = __builtin_bit_cast(short, (_Float16)(oac.z - (float)p23.x));
                rowp[9 + 4 * g + 3] = __builtin_bit_cast(short, (_Float16)(oac.w - (float)p23.y));
            } else if (g == 2) {
                short hh, ll; split_hl(oac.x, hh, ll);
                short* rowp = Gb + q * 40;
                rowp[8] = hh; rowp[17] = ll; rowp[26] = hh;
            }
        }
        // layer-top sync of next iteration protects Gb->Xb handoff
    }
    __syncthreads();

    // ---- logits + log_softmax from BUF0 (final X after 4 ping-pongs) ----
    if (tid < 128) {
        const int r = tid;
        const short* rowp = BUF0 + r * 40;
        hv8 ha = __builtin_bit_cast(hv8, *(const u4v*)rowp);          // slots 0..7
        hv8 hb = __builtin_bit_cast(hv8, *(const u4v*)(rowp + 8));    // slots 8..15
        h2  hc = __builtin_bit_cast(h2, *(const unsigned*)(rowp + 16)); // 16,17
        float x[9];
        x[0] = (float)ha[0] + (float)hb[1];
        x[1] = (float)ha[1] + (float)hb[2];
        x[2] = (float)ha[2] + (float)hb[3];
        x[3] = (float)ha[3] + (float)hb[4];
        x[4] = (float)ha[4] + (float)hb[5];
        x[5] = (float)ha[5] + (float)hb[6];
        x[6] = (float)ha[6] + (float)hb[7];
        x[7] = (float)ha[7] + (float)hc.x;
        x[8] = (float)hb[0] + (float)hc.y;
        float lg[Vn];
        #pragma unroll
        for (int v = 0; v < Vn; ++v) {
            float a = bout[v];
            #pragma unroll
            for (int d = 0; d < Dn; ++d) a = fmaf(x[d], Wout[v * Dn + d], a);
            lg[v] = a;
        }
        float mm = lg[0];
        #pragma unroll
        for (int v = 1; v < Vn; ++v) mm = fmaxf(mm, lg[v]);
        float sum = 0.0f;
        #pragma unroll
        for (int v = 0; v < Vn; ++v)
            sum += __builtin_amdgcn_exp2f((lg[v] - mm) * 1.44269504f);
        const float lse = __builtin_amdgcn_logf(sum) * 0.69314718f + mm;
        float* op = out + ((size_t)b * Sn + r) * Vn;
        #pragma unroll
        for (int v = 0; v < Vn; ++v) op[v] = lg[v] - lse;
    }
}

extern "C" void kernel_launch(void* const* d_in, const int* in_sizes, int n_in,
                              void* d_out, int out_size, void* d_ws, size_t ws_size,
                              hipStream_t stream) {
    const int*   tokens = (const int*)  d_in[0];
    const float* emb    = (const float*)d_in[1];
    const float* Wq     = (const float*)d_in[2];
    const float* bq_    = (const float*)d_in[3];
    const float* Wk     = (const float*)d_in[4];
    const float* bk_    = (const float*)d_in[5];
    const float* Wv     = (const float*)d_in[6];
    const float* bv_    = (const float*)d_in[7];
    const float* Wout   = (const float*)d_in[8];
    const float* bout_  = (const float*)d_in[9];
    float* out = (float*)d_out;

    bert_kernel<<<dim3(Bn), dim3(256), 0, stream>>>(
        tokens, emb, Wq, bq_, Wk, bk_, Wv, bv_, Wout, bout_, out);
}